// Round 8
// baseline (1803.804 us; speedup 1.0000x reference)
//
#include <hip/hip_runtime.h>

// PSGIN forward on MI355X. fp32 I/O.
// R2: no prop + dual-weight GEMM in one kernel (spill). R3: attention occupancy + cheap tanh.
// R4: aligned vector staging, stride-208. R5/R6: double-buffer K-loops. R6: attn 2x2 + clampless
// Pade; drop P^2. R7 lesson: 44 serial dispatches x ~15us each; phases are latency-bound, not
// compute-bound -> R8: persistent megakernel for the 6 cells. Cells are batch-independent; each
// phase boundary is all-to-all over only 26 blocks/batch -> per-batch software barrier
// (device-scope atomics, one-shot slots, memset-zeroed) replaces ~36 launches. Grid (13,8,2)=208
// blocks <= 256 CUs => co-residency guaranteed. z-gate lives in registers across phases.

constexpr int B = 8, T = 24, N = 207, F = 16, H = 64, DH = 16;
constexpr int PS = 208; // padded stride for N x N matrices
constexpr float ALPHA = 0.05f, BETA = 0.95f, GAMMA = 0.95f, TA = 2.0f;
constexpr int NF = N * F;      // 3312
constexpr int BNF = B * N * F; // 26496

__device__ __forceinline__ float tanh_fast(float x) { float e = __expf(2.f * x); return 1.f - 2.f / (e + 1.f); }
__device__ __forceinline__ float sigm(float x) { return 1.f / (1.f + __expf(-x)); }
// clampless Pade 3/2 tanh: valid for |x| <~ 3; attention scores are |q+k| < ~1
__device__ __forceinline__ float tanh_pnc(float x) {
    float x2 = x * x;
    float p = x * (27.f + x2);
    float q = 27.f + 9.f * x2;
    return p * __builtin_amdgcn_rcpf(q);
}

// per-batch software barrier: 26 blocks, one-shot slot (zeroed by memset each launch)
__device__ __forceinline__ void bbar(unsigned* slot) {
    __syncthreads();
    if (threadIdx.x == 0) {
        __threadfence();
        __hip_atomic_fetch_add(slot, 1u, __ATOMIC_ACQ_REL, __HIP_MEMORY_SCOPE_AGENT);
        while (__hip_atomic_load(slot, __ATOMIC_ACQUIRE, __HIP_MEMORY_SCOPE_AGENT) < 26u)
            __builtin_amdgcn_s_sleep(2);
        __threadfence();
    }
    __syncthreads();
}

// ---------------- Ts[w*PS+v] = static_adj[v*N+w] ----------------
__global__ __launch_bounds__(256) void k_build_Ts(const float* __restrict__ adj, float* __restrict__ Ts) {
    int i = blockIdx.x * 256 + threadIdx.x;
    if (i >= N * N) return;
    int w = i / N, v = i % N;
    Ts[(size_t)w * PS + v] = adj[v * N + w];
}

// ---------------- square: Aout = Ain @ Ain (stride PS, double-buffered; one-time A2) ----------------
__global__ __launch_bounds__(256) void k_mm_sq(const float* __restrict__ Ain, float* __restrict__ Aout) {
    const float* A = Ain;
    float* O = Aout;
    int w0 = blockIdx.x * 32, v0b = blockIdx.y * 32;
    int tid = threadIdx.x;
    __shared__ float sA[2][32][33], sB[2][32][33];
    float acc[4] = {0, 0, 0, 0};
    int i0 = tid >> 5, j = tid & 31;
    int r = tid >> 3, c4 = (tid & 7) * 4;
    float4 av, bv;
    auto loadT = [&](int u0) {
        av = make_float4(0, 0, 0, 0); bv = make_float4(0, 0, 0, 0);
        int w = w0 + r, u = u0 + r;
        if (w < N) av = *(const float4*)&A[(size_t)w * PS + u0 + c4];
        if (u < N) bv = *(const float4*)&A[(size_t)u * PS + v0b + c4];
    };
    loadT(0);
    int cur = 0;
    for (int t = 0; t < 7; t++) {
        __syncthreads();
        sA[cur][r][c4] = av.x; sA[cur][r][c4 + 1] = av.y; sA[cur][r][c4 + 2] = av.z; sA[cur][r][c4 + 3] = av.w;
        sB[cur][r][c4] = bv.x; sB[cur][r][c4 + 1] = bv.y; sB[cur][r][c4 + 2] = bv.z; sB[cur][r][c4 + 3] = bv.w;
        if (t < 6) loadT((t + 1) * 32);
        __syncthreads();
#pragma unroll 8
        for (int u_ = 0; u_ < 32; u_++) {
            float bvv = sB[cur][u_][j];
#pragma unroll
            for (int k = 0; k < 4; k++) acc[k] += sA[cur][i0 + k * 8][u_] * bvv;
        }
        cur ^= 1;
    }
#pragma unroll
    for (int k = 0; k < 4; k++) {
        int w = w0 + i0 + k * 8, v = v0b + j;
        if (w < N && v < N) O[(size_t)w * PS + v] = acc[k];
    }
}

// =====================================================================================
// Megakernel: runs ncells GRU cells. grid (13, 8, 2) = 208 blocks.
// Phases per cell (bbar after each):
//  ph0 cell_a (lane0: src proj + gi, lane1: tgt proj; hyper chain duplicated)
//  ph1 cell_bP (lane0 only) -> P
//  ph2 h1 = a*x + P@x      (catg cols 80..160; lane = col half)
//  ph3 h2 = a*x + P@h1     (catg cols 160..240)
//  ph4 gates: lane0 z (kept in REGISTERS), lane1 r -> catc[x | r*h]
//  ph5 h1' on catc ; ph6 h2' on catc
//  ph7 gate c (lane0) + h update (+ final heads)
// =====================================================================================
__global__ __launch_bounds__(256) void k_mega(
    int ncells, int t0, const float* __restrict__ xbuf, int finalFlag,
    unsigned* __restrict__ bars, int barBase,
    const float* __restrict__ inp, const float* __restrict__ adj,
    const float* __restrict__ Ts, const float* __restrict__ A2,
    const float* __restrict__ Wsrc, const float* __restrict__ bsrc,
    const float* __restrict__ Wtgt, const float* __restrict__ btgt,
    const float* __restrict__ Wes, const float* __restrict__ bes,
    const float* __restrict__ Wet, const float* __restrict__ bet,
    const float* __restrict__ Wz, const float* __restrict__ bz,
    const float* __restrict__ Wr, const float* __restrict__ br,
    const float* __restrict__ Wc, const float* __restrict__ bc,
    const float* __restrict__ Wlong, const float* __restrict__ blong,
    const float* __restrict__ Wfus, const float* __restrict__ bfus,
    float* __restrict__ h, float* __restrict__ sbuf, float* __restrict__ tbuf,
    float* __restrict__ P, float* __restrict__ catg, float* __restrict__ catc,
    const float* __restrict__ target, float* __restrict__ out)
{
    __shared__ __align__(16) float smem[13312];
    const int wb = blockIdx.x, b = blockIdx.y, lane = blockIdx.z;
    const int tid = threadIdx.x, ty = tid >> 4, tx = tid & 15;
    const int w0 = wb * 16;
    unsigned* bb = bars + b * 96 + barBase;
    int bi = 0;
    float* hb = h + (size_t)b * N * H;
    float* Pb = P + (size_t)b * PS * PS;
    float zreg[4] = {0.f, 0.f, 0.f, 0.f};

    // prop: cat[dstOff + c] = ALPHA*cat[c] + P @ cat[srcOff + c], this lane's 40-col half
    auto prop = [&](float* cat, int srcOff, int dstOff) {
        float* sP = smem;              // [16][208]
        float* sX = smem + 16 * 208;   // [208][48] (cols 0..39 staged)
        for (int l4 = tid; l4 < 832; l4 += 256) {
            int r = l4 / 52, c4 = (l4 % 52) * 4;
            float4 v = make_float4(0.f, 0.f, 0.f, 0.f);
            int w = w0 + r;
            if (w < N) v = *(const float4*)&Pb[(size_t)w * PS + c4];
            *(float4*)&sP[r * 208 + c4] = v;
        }
        int cbase = srcOff + lane * 40;
        for (int l4 = tid; l4 < 2080; l4 += 256) {
            int r = l4 / 10, q = (l4 % 10) * 4;
            float4 v = make_float4(0.f, 0.f, 0.f, 0.f);
            if (r < N) v = *(const float4*)&cat[((size_t)(b * N + r)) * 240 + cbase + q];
            *(float4*)&sX[r * 48 + q] = v;
        }
        __syncthreads();
        if (tid < 16) sP[tid * 208 + 207] = 0.f;  // PS pad column may hold poison
        __syncthreads();
        float acc0 = 0.f, acc1 = 0.f, acc2 = 0.f;
        for (int v = 0; v < 208; v += 4) {
#pragma unroll
            for (int u = 0; u < 4; u++) {
                float p = sP[ty * 208 + v + u];
                const float* xr = &sX[(v + u) * 48];
                acc0 += p * xr[tx];
                acc1 += p * xr[16 + tx];
                acc2 += p * xr[32 + tx];   // cols >=40 unstaged; discarded for tx>=8
            }
        }
        int w = w0 + ty;
        if (w < N) {
            size_t row = ((size_t)(b * N + w)) * 240;
            int cl = lane * 40;
            cat[row + dstOff + cl + tx] = ALPHA * cat[row + cl + tx] + acc0;
            cat[row + dstOff + cl + 16 + tx] = ALPHA * cat[row + cl + 16 + tx] + acc1;
            if (tx < 8) cat[row + dstOff + cl + 32 + tx] = ALPHA * cat[row + cl + 32 + tx] + acc2;
        }
    };

    // gate GEMM: ga = bias + cat_row[240] @ W[240,64]
    auto gate = [&](const float* cat, const float* W, const float* bias, float* ga) {
        float* sC = smem;           // [16][241]
        float* sW = smem + 3856;    // [48][65]
        for (int l4 = tid; l4 < 960; l4 += 256) {
            int r = l4 / 60, c4 = (l4 % 60) * 4;
            float4 v = make_float4(0.f, 0.f, 0.f, 0.f);
            int w = w0 + r;
            if (w < N) v = *(const float4*)&cat[((size_t)(b * N + w)) * 240 + c4];
            sC[r * 241 + c4] = v.x; sC[r * 241 + c4 + 1] = v.y; sC[r * 241 + c4 + 2] = v.z; sC[r * 241 + c4 + 3] = v.w;
        }
        float4 wv[3];
#pragma unroll
        for (int k = 0; k < 3; k++) wv[k] = *(const float4*)&W[(tid + k * 256) * 4];
#pragma unroll
        for (int j = 0; j < 4; j++) ga[j] = bias[tx * 4 + j];
        for (int ch = 0; ch < 5; ch++) {
            __syncthreads();
#pragma unroll
            for (int k = 0; k < 3; k++) {
                int l4 = tid + k * 256;
                int r = l4 >> 4, cc = (l4 & 15) * 4;
                sW[r * 65 + cc] = wv[k].x; sW[r * 65 + cc + 1] = wv[k].y;
                sW[r * 65 + cc + 2] = wv[k].z; sW[r * 65 + cc + 3] = wv[k].w;
            }
            if (ch < 4) {
#pragma unroll
                for (int k = 0; k < 3; k++) wv[k] = *(const float4*)&W[(size_t)(ch + 1) * 3072 + (tid + k * 256) * 4];
            }
            __syncthreads();
            int c0 = ch * 48;
#pragma unroll 8
            for (int cc = 0; cc < 48; cc++) {
                float cv = sC[ty * 241 + c0 + cc];
#pragma unroll
                for (int j = 0; j < 4; j++) ga[j] += cv * sW[cc * 65 + tx * 4 + j];
            }
        }
    };

    for (int cell = 0; cell < ncells; cell++) {
        int tsel = (t0 >= 0) ? (t0 + 4 * cell) : -1;
        const float* xp = (tsel >= 0) ? (inp + ((size_t)(b * T + tsel)) * NF) : (xbuf + (size_t)b * NF);

        // ================= ph0: cell_a =================
        {
            // smem: sTs[2][16][33]@0, sA2@1056, sH[2][32][64]@2112, cat[16][193]@6208,
            //       sW[192][16]@9296, sX[16][16]@12368, sWe[16][16]@12624
            float au[4] = {0, 0, 0, 0}, aw[4] = {0, 0, 0, 0};
            int pidx = tid & 127;
            int pr = pidx >> 3, pc4 = (pidx & 7) * 4;
            float4 t4;
            float4 h4[2];
            int hr[2], hc[2];
#pragma unroll
            for (int k = 0; k < 2; k++) { int l4 = tid + k * 256; hr[k] = l4 >> 4; hc[k] = (l4 & 15) * 4; }
            auto loadT = [&](int v0) {
                t4 = make_float4(0, 0, 0, 0);
                const float* src = (tid < 128) ? Ts : A2;
                int w = w0 + pr;
                if (w < N) t4 = *(const float4*)&src[(size_t)w * PS + v0 + pc4];
#pragma unroll
                for (int k = 0; k < 2; k++) {
                    float4 hv = make_float4(0, 0, 0, 0);
                    int v = v0 + hr[k];
                    if (v < N) hv = *(const float4*)&hb[(size_t)v * H + hc[k]];
                    h4[k] = hv;
                }
            };
            loadT(0);
            int cur = 0;
            for (int t = 0; t < 7; t++) {
                __syncthreads();
                {
                    float* dst = (tid < 128) ? (smem + cur * 528) : (smem + 1056 + cur * 528);
                    dst[pr * 33 + pc4] = t4.x; dst[pr * 33 + pc4 + 1] = t4.y;
                    dst[pr * 33 + pc4 + 2] = t4.z; dst[pr * 33 + pc4 + 3] = t4.w;
                }
#pragma unroll
                for (int k = 0; k < 2; k++) *(float4*)&smem[2112 + cur * 2048 + hr[k] * 64 + hc[k]] = h4[k];
                if (t < 6) loadT((t + 1) * 32);
                __syncthreads();
#pragma unroll 8
                for (int v = 0; v < 32; v++) {
                    float pu = smem[cur * 528 + ty * 33 + v];
                    float pw = smem[1056 + cur * 528 + ty * 33 + v];
#pragma unroll
                    for (int j = 0; j < 4; j++) {
                        float x = smem[2112 + cur * 2048 + v * 64 + tx * 4 + j];
                        au[j] += pu * x; aw[j] += pw * x;
                    }
                }
                cur ^= 1;
            }
            int w = w0 + ty;
            bool valid = w < N;
            __syncthreads();
            float* catL = smem + 6208;
            if (valid) {
#pragma unroll
                for (int j = 0; j < 4; j++) {
                    int c = tx * 4 + j;
                    float hv = hb[(size_t)w * H + c];
                    float u = au[j], w2 = aw[j];
                    catL[ty * 193 + c] = hv;
                    catL[ty * 193 + 64 + c] = ALPHA * hv + GAMMA * u;
                    catL[ty * 193 + 128 + c] = ALPHA * hv + ALPHA * GAMMA * u + GAMMA * GAMMA * w2;
                }
            } else {
#pragma unroll
                for (int j = 0; j < 4; j++) {
                    int c = tx * 4 + j;
                    catL[ty * 193 + c] = 0; catL[ty * 193 + 64 + c] = 0; catL[ty * 193 + 128 + c] = 0;
                }
            }
            const float* Wg = lane ? Wtgt : Wsrc;
            const float* bg = lane ? btgt : bsrc;
            const float* We = lane ? Wet : Wes;
            const float* be = lane ? bet : bes;
            {
                float4 wv[3];
#pragma unroll
                for (int k = 0; k < 3; k++) wv[k] = *(const float4*)&Wg[(tid + k * 256) * 4];
                float4 xv = make_float4(0, 0, 0, 0), ev = make_float4(0, 0, 0, 0);
                int sr = 0, sc = 0;
                if (tid < 64) {
                    sr = tid >> 2; sc = (tid & 3) * 4;
                    int n = w0 + sr;
                    if (n < N) xv = *(const float4*)&xp[(size_t)n * F + sc];
                    ev = *(const float4*)&We[tid * 4];
                }
#pragma unroll
                for (int k = 0; k < 3; k++) {
                    int l4 = tid + k * 256;
                    int r = l4 >> 2, c4 = (l4 & 3) * 4;
                    *(float4*)&smem[9296 + r * 16 + c4] = wv[k];
                }
                if (tid < 64) {
                    *(float4*)&smem[12368 + sr * 16 + sc] = xv;
                    *(float4*)&smem[12624 + sr * 16 + sc] = ev;
                }
            }
            __syncthreads();
            if (lane == 0 && valid) {
#pragma unroll
                for (int j = 0; j < 5; j++) {
                    int c = tx * 5 + j;
                    float v = (c < 16) ? smem[12368 + ty * 16 + c] : hb[(size_t)w * H + (c - 16)];
                    catg[((size_t)(b * N + w)) * 240 + c] = v;
                }
            }
            {
                float ctx = bg[tx];
#pragma unroll 8
                for (int c = 0; c < 192; c++) ctx += catL[ty * 193 + c] * smem[9296 + c * 16 + tx];
                float xe = be[tx];
#pragma unroll
                for (int f = 0; f < 16; f++) xe += smem[12368 + ty * 16 + f] * smem[12624 + f * 16 + tx];
                if (valid) {
                    float val = tanh_fast(TA * xe * ctx);
                    if (lane == 0) sbuf[(size_t)(b * N + w) * DH + tx] = val;
                    else           tbuf[(size_t)(b * N + w) * DH + tx] = val;
                }
            }
        }
        bbar(&bb[bi++]);

        // ================= ph1: cell_bP (lane0) =================
        if (lane == 0) {
            float* sS = smem;            // [207][17]
            float* sT = smem + 3519;     // [207][17]
            for (int l4 = tid; l4 < 828; l4 += 256) {
                float4 sv = *(const float4*)&sbuf[(size_t)b * N * 16 + l4 * 4];
                float4 tv = *(const float4*)&tbuf[(size_t)b * N * 16 + l4 * 4];
                int r = l4 >> 2, c = (l4 & 3) * 4;
                sS[r * 17 + c] = sv.x; sS[r * 17 + c + 1] = sv.y; sS[r * 17 + c + 2] = sv.z; sS[r * 17 + c + 3] = sv.w;
                sT[r * 17 + c] = tv.x; sT[r * 17 + c + 1] = tv.y; sT[r * 17 + c + 2] = tv.z; sT[r * 17 + c + 3] = tv.w;
            }
            __syncthreads();
            int v = w0 + ty;
            bool valid = v < N;
            int vc = valid ? v : (N - 1);
            float sv[16], tv[16];
#pragma unroll
            for (int k = 0; k < 16; k++) { sv[k] = sS[vc * 17 + k]; tv[k] = sT[vc * 17 + k]; }
            float val[13];
            float rsum = 0.f;
#pragma unroll
            for (int idx = 0; idx < 13; idx++) {
                int w = tx + 16 * idx;
                float r = 0.f;
                if (w < N) {
                    float a = 0.f;
#pragma unroll
                    for (int k = 0; k < 16; k++) a += sv[k] * sT[w * 17 + k] - tv[k] * sS[w * 17 + k];
                    r = tanh_fast(TA * a);
                    r = r > 0.f ? r : 0.f;
                    if (w == v) r += 1.f;
                }
                val[idx] = r;
                rsum += r;
            }
            float tot = rsum;
            for (int d = 8; d > 0; d >>= 1) tot += __shfl_down(tot, d, 16);
            tot = __shfl(tot, 0, 16);
            float rinv = BETA / (tot + 1e-8f);
            if (valid) {
#pragma unroll
                for (int idx = 0; idx < 13; idx++) {
                    int w = tx + 16 * idx;
                    if (w < N) Pb[(size_t)w * PS + v] = val[idx] * rinv + GAMMA * adj[v * N + w];
                }
            }
        }
        bbar(&bb[bi++]);

        // ================= ph2/ph3: h1, h2 on catg =================
        prop(catg, 0, 80);
        bbar(&bb[bi++]);
        prop(catg, 80, 160);
        bbar(&bb[bi++]);

        // ================= ph4: gates z (lane0, regs) / r (lane1 -> catc) =================
        {
            float ga[4];
            if (lane == 0) {
                gate(catg, Wz, bz, ga);
#pragma unroll
                for (int j = 0; j < 4; j++) zreg[j] = sigm(ga[j]);
            } else {
                gate(catg, Wr, br, ga);
                int w = w0 + ty;
                if (w < N) {
#pragma unroll
                    for (int j = 0; j < 4; j++) {
                        int o = tx * 4 + j;
                        catc[((size_t)(b * N + w)) * 240 + 16 + o] = sigm(ga[j]) * hb[(size_t)w * H + o];
                    }
                    if (tx < 4) {
#pragma unroll
                        for (int j = 0; j < 4; j++) {
                            int c = tx * 4 + j;
                            catc[((size_t)(b * N + w)) * 240 + c] = xp[w * F + c];
                        }
                    }
                }
            }
        }
        bbar(&bb[bi++]);

        // ================= ph5/ph6: h1', h2' on catc =================
        prop(catc, 0, 80);
        bbar(&bb[bi++]);
        prop(catc, 80, 160);
        bbar(&bb[bi++]);

        // ================= ph7: gate c (lane0) + h update (+ heads) =================
        if (lane == 0) {
            float ga[4];
            gate(catc, Wc, bc, ga);
            float* hrow = smem + 6976;   // [16][65]
            float* trow = smem + 8016;   // [16][65]
            int w = w0 + ty;
            bool valid = w < N;
#pragma unroll
            for (int j = 0; j < 4; j++) {
                int o = tx * 4 + j;
                float cval = tanh_fast(ga[j]);
                float hv = valid ? hb[(size_t)w * H + o] : 0.f;
                float hn = zreg[j] * hv + (1.f - zreg[j]) * cval;
                if (valid) hb[(size_t)w * H + o] = hn;
                hrow[ty * 65 + o] = valid ? hn : 0.f;
            }
            if (finalFlag && cell == ncells - 1) {
                for (int l = tid; l < 1024; l += 256) {
                    int i = l >> 6, o = l & 63;
                    int ww = w0 + i;
                    trow[i * 65 + o] = (ww < N) ? target[((size_t)(b * N + ww)) * 64 + o] : 0.f;
                }
                __syncthreads();
                float lg = blong[tx], fs = bfus[tx];
#pragma unroll 8
                for (int o = 0; o < 64; o++) {
                    lg += hrow[ty * 65 + o] * Wlong[o * 16 + tx];
                    fs += trow[ty * 65 + o] * Wfus[o * 16 + tx] + hrow[ty * 65 + o] * Wfus[(64 + o) * 16 + tx];
                }
                if (valid) {
                    out[((size_t)1 * B * N + b * N + w) * 16 + tx] = lg;
                    out[((size_t)2 * B * N + b * N + w) * 16 + tx] = fs;
                }
            }
        }
        bbar(&bb[bi++]);
    }
}

// ---------------- attention: fused q/k proj + 32x32 tile, 2x2/thread, clampless Pade ----------------
__global__ __launch_bounds__(256) void k_attn2(const float* __restrict__ inp,
                                               const float* __restrict__ Wq, const float* __restrict__ Wk,
                                               const float* __restrict__ kb, const float* __restrict__ sw_,
                                               float* __restrict__ attnU, float* __restrict__ rsum) {
    int bt = blockIdx.z, b = bt >> 2, tau = bt & 3;
    int n0 = blockIdx.x * 32, m0 = blockIdx.y * 32;
    int tid = threadIdx.x, ti = tid >> 4, tj = tid & 15;
    __shared__ float sQ[32][65], sK[32][65];
    __shared__ float sWq[16][64], sWk[16][64];
    __shared__ float sXq[32][17], sXk[32][17];
    __shared__ float ssw[64], skb[64];
    const float* xq = inp + ((size_t)(b * T + (T - 1))) * NF;
    const float* xk = inp + ((size_t)(b * T + 20 + tau)) * NF;
    {
        float4 wq4 = *(const float4*)&Wq[tid * 4];
        float4 wk4 = *(const float4*)&Wk[tid * 4];
        *(float4*)&sWq[tid >> 4][(tid & 15) * 4] = wq4;
        *(float4*)&sWk[tid >> 4][(tid & 15) * 4] = wk4;
        if (tid < 64) { ssw[tid] = sw_[tid]; skb[tid] = kb[tid]; }
        int idx = tid & 127;
        int r = idx >> 2, c4 = (idx & 3) * 4;
        if (tid < 128) {
            float4 a = make_float4(0, 0, 0, 0);
            int n = n0 + r;
            if (n < N) a = *(const float4*)&xq[(size_t)n * F + c4];
            sXq[r][c4] = a.x; sXq[r][c4 + 1] = a.y; sXq[r][c4 + 2] = a.z; sXq[r][c4 + 3] = a.w;
        } else {
            float4 c = make_float4(0, 0, 0, 0);
            int m = m0 + r;
            if (m < N) c = *(const float4*)&xk[(size_t)m * F + c4];
            sXk[r][c4] = c.x; sXk[r][c4 + 1] = c.y; sXk[r][c4 + 2] = c.z; sXk[r][c4 + 3] = c.w;
        }
    }
    __syncthreads();
    {
        int r = tid >> 3, o0 = (tid & 7) * 8;
        float xr[16], xkr[16];
#pragma unroll
        for (int f = 0; f < 16; f++) { xr[f] = sXq[r][f]; xkr[f] = sXk[r][f]; }
#pragma unroll
        for (int j = 0; j < 8; j++) {
            int o = o0 + j;
            float aq = 0.f, ak = skb[o];
#pragma unroll
            for (int f = 0; f < 16; f++) { aq += xr[f] * sWq[f][o]; ak += xkr[f] * sWk[f][o]; }
            sQ[r][o] = aq; sK[r][o] = ak;
        }
    }
    __syncthreads();
    float s00 = 0.f, s01 = 0.f, s10 = 0.f, s11 = 0.f;
#pragma unroll 2
    for (int d = 0; d < 64; d++) {
        float w = ssw[d];
        float q1 = sQ[ti][d], q2 = sQ[ti + 16][d];
        float k1 = sK[tj][d], k2 = sK[tj + 16][d];
        s00 += tanh_pnc(q1 + k1) * w;
        s01 += tanh_pnc(q1 + k2) * w;
        s10 += tanh_pnc(q2 + k1) * w;
        s11 += tanh_pnc(q2 + k2) * w;
    }
    int n1 = n0 + ti, n2 = n0 + ti + 16, m1 = m0 + tj, m2 = m0 + tj + 16;
    bool vn1 = n1 < N, vn2 = n2 < N, vm1 = m1 < N, vm2 = m2 < N;
    float e00 = (vn1 && vm1) ? __expf(s00) : 0.f;
    float e01 = (vn1 && vm2) ? __expf(s01) : 0.f;
    float e10 = (vn2 && vm1) ? __expf(s10) : 0.f;
    float e11 = (vn2 && vm2) ? __expf(s11) : 0.f;
    float part1 = e00 + e01, part2 = e10 + e11;
    for (int d = 8; d > 0; d >>= 1) {
        part1 += __shfl_down(part1, d, 16);
        part2 += __shfl_down(part2, d, 16);
    }
    if (tj == 0) {
        if (vn1) atomicAdd(&rsum[bt * N + n1], part1);
        if (vn2) atomicAdd(&rsum[bt * N + n2], part2);
    }
    size_t base = (size_t)bt * PS * PS;
    if (vn1 && vm1) attnU[base + (size_t)n1 * PS + m1] = e00;
    if (vn1 && vm2) attnU[base + (size_t)n1 * PS + m2] = e01;
    if (vn2 && vm1) attnU[base + (size_t)n2 * PS + m1] = e10;
    if (vn2 && vm2) attnU[base + (size_t)n2 * PS + m2] = e11;
}

// ---------------- transpose-combine: Pout[w,v] = cA*Ain[v,w]/rs[v] + cT*Ts[w,v] ----------------
__global__ __launch_bounds__(256) void k_combineT(const float* __restrict__ Ain, const float* __restrict__ rs,
                                                  const float* __restrict__ Ts, float* __restrict__ Pout,
                                                  float cA, float cT) {
    int bt = blockIdx.z;
    int w0 = blockIdx.x * 32, v0 = blockIdx.y * 32;
    int tid = threadIdx.x;
    __shared__ float tile[32][33];
    __shared__ float rsv[32];
    int r = tid >> 3, c4 = (tid & 7) * 4;
    float4 a4 = make_float4(0, 0, 0, 0);
    int v = v0 + r;
    if (v < N) a4 = *(const float4*)&Ain[(size_t)bt * PS * PS + (size_t)v * PS + w0 + c4];
    tile[r][c4] = a4.x; tile[r][c4 + 1] = a4.y; tile[r][c4 + 2] = a4.z; tile[r][c4 + 3] = a4.w;
    if (tid < 32) {
        int vv = v0 + tid;
        rsv[tid] = (vv < N) ? (cA / rs[bt * N + vv]) : 0.f;
    }
    __syncthreads();
    for (int l = tid; l < 1024; l += 256) {
        int i = l >> 5, j = l & 31;
        int w = w0 + i, vv = v0 + j;
        if (w < N && vv < N)
            Pout[(size_t)bt * PS * PS + (size_t)w * PS + vv] = tile[j][i] * rsv[j] + cT * Ts[(size_t)w * PS + vv];
    }
}

// ---------------- ssgal first prop (double-buffered): x1 = a*x + Pd@x ----------------
__global__ __launch_bounds__(256) void k_prop_xr(const float* __restrict__ Pd, const float* __restrict__ inp,
                                                 float* __restrict__ x1) {
    int bt = blockIdx.y, w0 = blockIdx.x * 16;
    int b = bt >> 2, tau = bt & 3;
    const float* xb = inp + ((size_t)(b * T + 20 + tau)) * NF;
    const float* Pb = Pd + (size_t)bt * PS * PS;
    int tid = threadIdx.x, ty = tid >> 4, tx = tid & 15;
    __shared__ float sP[2][16][33];
    __shared__ float sX[2][32][17];
    float acc = 0.f;
    int prr = tid >> 3, pcc = (tid & 7) * 4;
    int xrr = (tid - 128) >> 2, xcc = ((tid - 128) & 3) * 4;
    float4 pv, xv;
    auto loadT = [&](int v0) {
        pv = make_float4(0, 0, 0, 0); xv = make_float4(0, 0, 0, 0);
        if (tid < 128) {
            int w = w0 + prr;
            if (w < N) pv = *(const float4*)&Pb[(size_t)w * PS + v0 + pcc];
        } else {
            int v = v0 + xrr;
            if (v < N) xv = *(const float4*)&xb[(size_t)v * F + xcc];
        }
    };
    loadT(0);
    int cur = 0;
    for (int t = 0; t < 7; t++) {
        __syncthreads();
        if (tid < 128) {
            sP[cur][prr][pcc] = pv.x; sP[cur][prr][pcc + 1] = pv.y; sP[cur][prr][pcc + 2] = pv.z; sP[cur][prr][pcc + 3] = pv.w;
        } else {
            sX[cur][xrr][xcc] = xv.x; sX[cur][xrr][xcc + 1] = xv.y; sX[cur][xrr][xcc + 2] = xv.z; sX[cur][xrr][xcc + 3] = xv.w;
        }
        if (t < 6) loadT((t + 1) * 32);
        __syncthreads();
#pragma unroll 8
        for (int v = 0; v < 32; v++) acc += sP[cur][ty][v] * sX[cur][v][tx];
        cur ^= 1;
    }
    int w = w0 + ty;
    if (w < N) x1[((size_t)(bt * N + w)) * 16 + tx] = ALPHA * xb[w * F + tx] + acc;
}

// ---------------- ssgal second prop + projection + relu + tau-sum (double-buffered) ----------------
__global__ __launch_bounds__(256) void k_sgc2(const float* __restrict__ Pd, const float* __restrict__ x1,
                                              const float* __restrict__ inp,
                                              const float* __restrict__ Ws, const float* __restrict__ bs,
                                              float* __restrict__ target) {
    int bt = blockIdx.y, b = bt >> 2, tau = bt & 3, w0 = blockIdx.x * 16;
    const float* xb = inp + ((size_t)(b * T + 20 + tau)) * NF;
    const float* Pb = Pd + (size_t)bt * PS * PS;
    int tid = threadIdx.x, ty = tid >> 4, tx = tid & 15;
    __shared__ float sP[2][16][33], sX[2][32][17], cat[16][48], sW[48][64];
    float acc = 0.f;
    int prr = tid >> 3, pcc = (tid & 7) * 4;
    int xrr = (tid - 128) >> 2, xcc = ((tid - 128) & 3) * 4;
    float4 pv, xv;
    auto loadT = [&](int v0) {
        pv = make_float4(0, 0, 0, 0); xv = make_float4(0, 0, 0, 0);
        if (tid < 128) {
            int w = w0 + prr;
            if (w < N) pv = *(const float4*)&Pb[(size_t)w * PS + v0 + pcc];
        } else {
            int v = v0 + xrr;
            if (v < N) xv = *(const float4*)&x1[((size_t)(bt * N + v)) * 16 + xcc];
        }
    };
    loadT(0);
    int cur = 0;
    for (int t = 0; t < 7; t++) {
        __syncthreads();
        if (tid < 128) {
            sP[cur][prr][pcc] = pv.x; sP[cur][prr][pcc + 1] = pv.y; sP[cur][prr][pcc + 2] = pv.z; sP[cur][prr][pcc + 3] = pv.w;
        } else {
            sX[cur][xrr][xcc] = xv.x; sX[cur][xrr][xcc + 1] = xv.y; sX[cur][xrr][xcc + 2] = xv.z; sX[cur][xrr][xcc + 3] = xv.w;
        }
        if (t < 6) loadT((t + 1) * 32);
        __syncthreads();
#pragma unroll 8
        for (int v = 0; v < 32; v++) acc += sP[cur][ty][v] * sX[cur][v][tx];
        cur ^= 1;
    }
    int w = w0 + ty;
    bool valid = w < N;
    __syncthreads();
    for (int l = tid; l < 512; l += 256) {
        int i = l >> 5, c = l & 31;
        int ww = w0 + i;
        float vv = 0;
        if (ww < N) {
            if (c < 16) vv = xb[ww * F + c];
            else vv = x1[((size_t)bt * N + ww) * 16 + (c - 16)];
        }
        cat[i][c] = vv;
    }
    {
        float x0 = valid ? xb[w * F + tx] : 0.f;
        cat[ty][32 + tx] = ALPHA * x0 + acc;
    }
    {
        float4 wv[3];
#pragma unroll
        for (int k = 0; k < 3; k++) wv[k] = *(const float4*)&Ws[(tid + k * 256) * 4];
#pragma unroll
        for (int k = 0; k < 3; k++) {
            int l4 = tid + k * 256;
            *(float4*)&sW[l4 >> 4][(l4 & 15) * 4] = wv[k];
        }
    }
    __syncthreads();
    float a[4];
#pragma unroll
    for (int j = 0; j < 4; j++) a[j] = bs[tx * 4 + j];
#pragma unroll 8
    for (int cc = 0; cc < 48; cc++) {
        float cv = cat[ty][cc];
#pragma unroll
        for (int j = 0; j < 4; j++) a[j] += cv * sW[cc][tx * 4 + j];
    }
    if (valid) {
#pragma unroll
        for (int j = 0; j < 4; j++) {
            float r = a[j] > 0.f ? a[j] : 0.f;
            atomicAdd(&target[(b * N + w) * 64 + tx * 4 + j], r);
        }
    }
}

// ---------------- short head ----------------
__global__ __launch_bounds__(256) void k_short(const float* __restrict__ target,
                                               const float* __restrict__ Wsh, const float* __restrict__ bsh,
                                               float* __restrict__ out, float* __restrict__ xshort) {
    int b = blockIdx.y, n0 = blockIdx.x * 16;
    int tid = threadIdx.x, ty = tid >> 4, tx = tid & 15;
    __shared__ float trow[16][65], sW[64][16];
    {
        int r = tid >> 4, c4 = (tid & 15) * 4;
        int n = n0 + r;
        float4 tv = make_float4(0, 0, 0, 0);
        if (n < N) tv = *(const float4*)&target[((size_t)(b * N + n)) * 64 + c4];
        trow[r][c4] = tv.x; trow[r][c4 + 1] = tv.y; trow[r][c4 + 2] = tv.z; trow[r][c4 + 3] = tv.w;
        float4 wv = *(const float4*)&Wsh[tid * 4];
        *(float4*)&sW[tid >> 2][(tid & 3) * 4] = wv;
    }
    __syncthreads();
    float a = bsh[tx];
#pragma unroll 8
    for (int o = 0; o < 64; o++) a += trow[ty][o] * sW[o][tx];
    int n = n0 + ty;
    if (n < N) {
        out[((size_t)0 * B * N + b * N + n) * 16 + tx] = a;
        xshort[(b * N + n) * 16 + tx] = a;
    }
}

extern "C" void kernel_launch(void* const* d_in, const int* in_sizes, int n_in,
                              void* d_out, int out_size, void* d_ws, size_t ws_size,
                              hipStream_t stream) {
    const float* inp = (const float*)d_in[0];
    const float* adj = (const float*)d_in[1];
    const float* src_gen_w = (const float*)d_in[2];
    const float* src_gen_b = (const float*)d_in[3];
    const float* tgt_gen_w = (const float*)d_in[4];
    const float* tgt_gen_b = (const float*)d_in[5];
    const float* src_emb_w = (const float*)d_in[6];
    const float* src_emb_b = (const float*)d_in[7];
    const float* tgt_emb_w = (const float*)d_in[8];
    const float* tgt_emb_b = (const float*)d_in[9];
    const float* gru_z_w = (const float*)d_in[10];
    const float* gru_z_b = (const float*)d_in[11];
    const float* gru_r_w = (const float*)d_in[12];
    const float* gru_r_b = (const float*)d_in[13];
    const float* gru_c_w = (const float*)d_in[14];
    const float* gru_c_b = (const float*)d_in[15];
    const float* attn_q_w = (const float*)d_in[16];
    const float* attn_k_w = (const float*)d_in[17];
    const float* attn_k_b = (const float*)d_in[18];
    const float* attn_s_w = (const float*)d_in[19];
    const float* sgcn_w = (const float*)d_in[20];
    const float* sgcn_b = (const float*)d_in[21];
    const float* short_w = (const float*)d_in[22];
    const float* short_b = (const float*)d_in[23];
    const float* long_w = (const float*)d_in[24];
    const float* long_b = (const float*)d_in[25];
    const float* fus_w = (const float*)d_in[26];
    const float* fus_b = (const float*)d_in[27];
    float* out = (float*)d_out;

    float* ws = (float*)d_ws;
    size_t off = 0;
    auto A = [&](size_t n) { n = (n + 3) & ~(size_t)3; float* p = ws + off; off += n; return p; };
    float* Ts = A((size_t)PS * PS);
    float* A2 = A((size_t)PS * PS);
    float* sbuf = A((size_t)B * N * DH);
    float* tbuf = A((size_t)B * N * DH);
    float* P = A((size_t)B * PS * PS);
    float* catg = A((size_t)B * N * 240);
    float* catc = A((size_t)B * N * 240);
    float* attnU = A((size_t)32 * PS * PS);
    float* Pd = A((size_t)32 * PS * PS);
    float* x1 = A((size_t)32 * NF);
    float* xshort = A(BNF);
    size_t zero_begin = off;
    float* h = A((size_t)B * N * H);
    float* target = A((size_t)B * N * 64);
    float* rsum = A((size_t)32 * N);
    float* barsf = A((size_t)8 * 96);
    size_t zero_end = off;
    unsigned* bars = (unsigned*)barsf;
    (void)ws_size; (void)in_sizes; (void)n_in; (void)out_size;

    // single memset zeroes h, target, rsum, barrier slots
    hipMemsetAsync(h, 0, (zero_end - zero_begin) * sizeof(float), stream);
    k_build_Ts<<<(N * N + 255) / 256, 256, 0, stream>>>(adj, Ts);
    k_mm_sq<<<dim3(7, 7), 256, 0, stream>>>(Ts, A2);

    k_mega<<<dim3(13, 8, 2), 256, 0, stream>>>(
        5, 0, nullptr, 0, bars, 0,
        inp, adj, Ts, A2,
        src_gen_w, src_gen_b, tgt_gen_w, tgt_gen_b, src_emb_w, src_emb_b, tgt_emb_w, tgt_emb_b,
        gru_z_w, gru_z_b, gru_r_w, gru_r_b, gru_c_w, gru_c_b,
        long_w, long_b, fus_w, fus_b,
        h, sbuf, tbuf, P, catg, catc, target, out);

    k_attn2<<<dim3(7, 7, 32), 256, 0, stream>>>(inp, attn_q_w, attn_k_w, attn_k_b, attn_s_w, attnU, rsum);
    k_combineT<<<dim3(7, 7, 32), 256, 0, stream>>>(attnU, rsum, Ts, Pd, GAMMA, GAMMA);
    k_prop_xr<<<dim3(13, 32), 256, 0, stream>>>(Pd, inp, x1);
    k_sgc2<<<dim3(13, 32), 256, 0, stream>>>(Pd, x1, inp, sgcn_w, sgcn_b, target);
    k_short<<<dim3(13, B), 256, 0, stream>>>(target, short_w, short_b, out, xshort);

    k_mega<<<dim3(13, 8, 2), 256, 0, stream>>>(
        1, -1, xshort, 1, bars, 48,
        inp, adj, Ts, A2,
        src_gen_w, src_gen_b, tgt_gen_w, tgt_gen_b, src_emb_w, src_emb_b, tgt_emb_w, tgt_emb_b,
        gru_z_w, gru_z_b, gru_r_w, gru_r_b, gru_c_w, gru_c_b,
        long_w, long_b, fus_w, fus_b,
        h, sbuf, tbuf, P, catg, catc, target, out);
}

// Round 9
// 645.552 us; speedup vs baseline: 2.7942x; 2.7942x over previous
//
#include <hip/hip_runtime.h>

// PSGIN forward on MI355X. fp32 I/O. Multi-kernel pipeline (R7 structure).
// R2: no prop + dual-weight GEMM in one kernel (VGPR spill). R3: attention occupancy + cheap tanh.
// R4: aligned vector staging, stride-208. R5/R6: double-buffer K-loops. R6: attn 2x2 + clampless
// Pade; drop P^2; fuse h2-prop into gate. R8 FAILED: persistent megakernel -> 256-VGPR spill +
// per-phase fence L2 invalidation (130MB fetch) + LDS conflicts => 2.7x regression. Kernel
// boundaries beat software barriers here. R9: revert to R7 + (a) cell_a lane-split (grid z=2),
// (b) attn2 writes transposed scores directly (LDS transpose), combineT eliminated,
// prop_xr/sgc2 do dual-accumulator (attnT/rs + Ts) prop, (c) merged memsets.

constexpr int B = 8, T = 24, N = 207, F = 16, H = 64, DH = 16;
constexpr int PS = 208; // padded stride for N x N matrices
constexpr float ALPHA = 0.05f, BETA = 0.95f, GAMMA = 0.95f, TA = 2.0f;
constexpr int NF = N * F;      // 3312
constexpr int BNF = B * N * F; // 26496

__device__ __forceinline__ float tanh_fast(float x) { float e = __expf(2.f * x); return 1.f - 2.f / (e + 1.f); }
__device__ __forceinline__ float sigm(float x) { return 1.f / (1.f + __expf(-x)); }
// clampless Pade 3/2 tanh: valid for |x| <~ 3; attention scores are |q+k| < ~1
__device__ __forceinline__ float tanh_pnc(float x) {
    float x2 = x * x;
    float p = x * (27.f + x2);
    float q = 27.f + 9.f * x2;
    return p * __builtin_amdgcn_rcpf(q);
}

// ---------------- Ts[w*PS+v] = static_adj[v*N+w] ----------------
__global__ __launch_bounds__(256) void k_build_Ts(const float* __restrict__ adj, float* __restrict__ Ts) {
    int i = blockIdx.x * 256 + threadIdx.x;
    if (i >= N * N) return;
    int w = i / N, v = i % N;
    Ts[(size_t)w * PS + v] = adj[v * N + w];
}

// ---------------- square: Aout = Ain @ Ain (stride PS; one-time A2) ----------------
__global__ __launch_bounds__(256) void k_mm_sq(const float* __restrict__ Ain, float* __restrict__ Aout) {
    const float* A = Ain;
    float* O = Aout;
    int w0 = blockIdx.x * 32, v0b = blockIdx.y * 32;
    int tid = threadIdx.x;
    __shared__ float sA[2][32][33], sB[2][32][33];
    float acc[4] = {0, 0, 0, 0};
    int i0 = tid >> 5, j = tid & 31;
    int r = tid >> 3, c4 = (tid & 7) * 4;
    float4 av, bv;
    auto loadT = [&](int u0) {
        av = make_float4(0, 0, 0, 0); bv = make_float4(0, 0, 0, 0);
        int w = w0 + r, u = u0 + r;
        if (w < N) av = *(const float4*)&A[(size_t)w * PS + u0 + c4];
        if (u < N) bv = *(const float4*)&A[(size_t)u * PS + v0b + c4];
    };
    loadT(0);
    int cur = 0;
    for (int t = 0; t < 7; t++) {
        __syncthreads();
        sA[cur][r][c4] = av.x; sA[cur][r][c4 + 1] = av.y; sA[cur][r][c4 + 2] = av.z; sA[cur][r][c4 + 3] = av.w;
        sB[cur][r][c4] = bv.x; sB[cur][r][c4 + 1] = bv.y; sB[cur][r][c4 + 2] = bv.z; sB[cur][r][c4 + 3] = bv.w;
        if (t < 6) loadT((t + 1) * 32);
        __syncthreads();
#pragma unroll 8
        for (int u_ = 0; u_ < 32; u_++) {
            float bvv = sB[cur][u_][j];
#pragma unroll
            for (int k = 0; k < 4; k++) acc[k] += sA[cur][i0 + k * 8][u_] * bvv;
        }
        cur ^= 1;
    }
#pragma unroll
    for (int k = 0; k < 4; k++) {
        int w = w0 + i0 + k * 8, v = v0b + j;
        if (w < N && v < N) O[(size_t)w * PS + v] = acc[k];
    }
}

// ---------------- cell stage A (lane-split): hyper chain + one projection per lane ----------------
// grid (13, B, 2): lane0 -> src proj + gi slice of catg -> sbuf; lane1 -> tgt proj -> tbuf
__global__ __launch_bounds__(256) void k_cell_a(
    const float* __restrict__ h, const float* __restrict__ Ts, const float* __restrict__ A2,
    const float* __restrict__ xseq, int tsel, const float* __restrict__ xbuf,
    const float* __restrict__ Wsrc, const float* __restrict__ bsrc,
    const float* __restrict__ Wtgt, const float* __restrict__ btgt,
    const float* __restrict__ Wes, const float* __restrict__ bes,
    const float* __restrict__ Wet, const float* __restrict__ bet,
    float* __restrict__ s_out, float* __restrict__ t_out, float* __restrict__ catg) {
    int b = blockIdx.y, w0 = blockIdx.x * 16, lane = blockIdx.z;
    int tid = threadIdx.x, ty = tid >> 4, tx = tid & 15;
    __shared__ float sTs[2][16][33], sA2[2][16][33];
    __shared__ float sH[2][32][64];
    __shared__ float cat[16][193];
    __shared__ float sW[192][16];
    __shared__ float sX[16][16], sWe[16][16];
    float au[4] = {0, 0, 0, 0}, aw[4] = {0, 0, 0, 0};
    const float* hb = h + b * N * H;
    const float* xp = (tsel >= 0) ? (xseq + ((size_t)(b * T + tsel)) * NF) : (xbuf + (size_t)b * NF);
    int pidx = tid & 127;
    int pr = pidx >> 3, pc4 = (pidx & 7) * 4;
    float4 t4;
    float4 h4[2];
    int hr[2], hc[2];
#pragma unroll
    for (int k = 0; k < 2; k++) { int l4 = tid + k * 256; hr[k] = l4 >> 4; hc[k] = (l4 & 15) * 4; }
    auto loadT = [&](int v0) {
        t4 = make_float4(0, 0, 0, 0);
        const float* src = (tid < 128) ? Ts : A2;
        int w = w0 + pr;
        if (w < N) t4 = *(const float4*)&src[(size_t)w * PS + v0 + pc4];
#pragma unroll
        for (int k = 0; k < 2; k++) {
            float4 hv = make_float4(0, 0, 0, 0);
            int v = v0 + hr[k];
            if (v < N) hv = *(const float4*)&hb[(size_t)v * H + hc[k]];
            h4[k] = hv;
        }
    };
    loadT(0);
    int cur = 0;
    for (int t = 0; t < 7; t++) {
        __syncthreads();
        {
            float (*dst)[33] = (tid < 128) ? sTs[cur] : sA2[cur];
            dst[pr][pc4] = t4.x; dst[pr][pc4 + 1] = t4.y; dst[pr][pc4 + 2] = t4.z; dst[pr][pc4 + 3] = t4.w;
        }
#pragma unroll
        for (int k = 0; k < 2; k++) *(float4*)&sH[cur][hr[k]][hc[k]] = h4[k];
        if (t < 6) loadT((t + 1) * 32);
        __syncthreads();
#pragma unroll 8
        for (int v = 0; v < 32; v++) {
            float pu = sTs[cur][ty][v], pw = sA2[cur][ty][v];
#pragma unroll
            for (int j = 0; j < 4; j++) {
                float x = sH[cur][v][tx * 4 + j];
                au[j] += pu * x; aw[j] += pw * x;
            }
        }
        cur ^= 1;
    }
    int w = w0 + ty;
    bool valid = w < N;
    __syncthreads();
    if (valid) {
#pragma unroll
        for (int j = 0; j < 4; j++) {
            int c = tx * 4 + j;
            float hv = hb[(size_t)w * H + c];
            float u = au[j], w2 = aw[j];
            cat[ty][c] = hv;
            cat[ty][64 + c] = ALPHA * hv + GAMMA * u;
            cat[ty][128 + c] = ALPHA * hv + ALPHA * GAMMA * u + GAMMA * GAMMA * w2;
        }
    } else {
#pragma unroll
        for (int j = 0; j < 4; j++) {
            int c = tx * 4 + j;
            cat[ty][c] = 0; cat[ty][64 + c] = 0; cat[ty][128 + c] = 0;
        }
    }
    const float* Wg = lane ? Wtgt : Wsrc;
    const float* bg = lane ? btgt : bsrc;
    const float* We = lane ? Wet : Wes;
    const float* be = lane ? bet : bes;
    {
        float4 wv[3];
#pragma unroll
        for (int k = 0; k < 3; k++) wv[k] = *(const float4*)&Wg[(tid + k * 256) * 4];
        float4 xv = make_float4(0, 0, 0, 0), ev = make_float4(0, 0, 0, 0);
        int sr = 0, sc = 0;
        if (tid < 64) {
            sr = tid >> 2; sc = (tid & 3) * 4;
            int n = w0 + sr;
            if (n < N) xv = *(const float4*)&xp[(size_t)n * F + sc];
            ev = *(const float4*)&We[tid * 4];
        }
#pragma unroll
        for (int k = 0; k < 3; k++) {
            int l4 = tid + k * 256;
            int r = l4 >> 2, c4 = (l4 & 3) * 4;
            *(float4*)&sW[r][c4] = wv[k];
        }
        if (tid < 64) {
            *(float4*)&sX[sr][sc] = xv;
            *(float4*)&sWe[sr][sc] = ev;
        }
    }
    __syncthreads();
    if (lane == 0 && valid) {
#pragma unroll
        for (int j = 0; j < 5; j++) {
            int c = tx * 5 + j;
            float v = (c < 16) ? sX[ty][c] : hb[(size_t)w * H + (c - 16)];
            catg[((size_t)(b * N + w)) * 240 + c] = v;
        }
    }
    {
        float ctx = bg[tx];
#pragma unroll 8
        for (int c = 0; c < 192; c++) ctx += cat[ty][c] * sW[c][tx];
        float xe = be[tx];
#pragma unroll
        for (int f = 0; f < 16; f++) xe += sX[ty][f] * sWe[f][tx];
        if (valid) {
            float val = tanh_fast(TA * xe * ctx);
            if (lane == 0) s_out[(size_t)(b * N + w) * DH + tx] = val;
            else           t_out[(size_t)(b * N + w) * DH + tx] = val;
        }
    }
}

// ---------------- cell stage B: adjacency rows + rowsum + direct P write (stride PS) ----------------
__global__ __launch_bounds__(256) void k_cell_bP(const float* __restrict__ s_in, const float* __restrict__ t_in,
                                                 const float* __restrict__ adj, float* __restrict__ P) {
    int b = blockIdx.y, v0 = blockIdx.x * 16;
    int tid = threadIdx.x, ty = tid >> 4, tx = tid & 15;
    __shared__ float sS[N][17], sT[N][17];
    for (int l4 = tid; l4 < 828; l4 += 256) {
        float4 sv = *(const float4*)&s_in[(size_t)b * N * 16 + l4 * 4];
        float4 tv = *(const float4*)&t_in[(size_t)b * N * 16 + l4 * 4];
        int r = l4 >> 2, c = (l4 & 3) * 4;
        sS[r][c] = sv.x; sS[r][c + 1] = sv.y; sS[r][c + 2] = sv.z; sS[r][c + 3] = sv.w;
        sT[r][c] = tv.x; sT[r][c + 1] = tv.y; sT[r][c + 2] = tv.z; sT[r][c + 3] = tv.w;
    }
    __syncthreads();
    int v = v0 + ty;
    bool valid = v < N;
    int vc = valid ? v : (N - 1);
    float sv[16], tv[16];
#pragma unroll
    for (int k = 0; k < 16; k++) { sv[k] = sS[vc][k]; tv[k] = sT[vc][k]; }
    float val[13];
    float rsum = 0.f;
#pragma unroll
    for (int idx = 0; idx < 13; idx++) {
        int w = tx + 16 * idx;
        float r = 0.f;
        if (w < N) {
            float a = 0.f;
#pragma unroll
            for (int k = 0; k < 16; k++) a += sv[k] * sT[w][k] - tv[k] * sS[w][k];
            r = tanh_fast(TA * a);
            r = r > 0.f ? r : 0.f;
            if (w == v) r += 1.f;
        }
        val[idx] = r;
        rsum += r;
    }
    float tot = rsum;
    for (int d = 8; d > 0; d >>= 1) tot += __shfl_down(tot, d, 16);
    tot = __shfl(tot, 0, 16);
    float rinv = BETA / (tot + 1e-8f);
    if (valid) {
        float* Pb = P + (size_t)b * PS * PS;
#pragma unroll
        for (int idx = 0; idx < 13; idx++) {
            int w = tx + 16 * idx;
            if (w < N) Pb[(size_t)w * PS + v] = val[idx] * rinv + GAMMA * adj[v * N + w];
        }
    }
}

// ---------------- single prop (double-buffered): cat[80..160] = a*cat[0..80] + P@cat[0..80] ----------------
__global__ __launch_bounds__(256) void k_prop1(const float* __restrict__ P, float* __restrict__ cat) {
    int b = blockIdx.y, w0 = blockIdx.x * 16, c0 = blockIdx.z * 16;
    int tid = threadIdx.x, ty = tid >> 4, tx = tid & 15;
    const float* Pb = P + (size_t)b * PS * PS;
    __shared__ float sP[2][16][33], sX[2][32][17];
    float a1 = 0.f;
    int pr = tid >> 4, pc = (tid & 15) * 2;
    int xr = tid >> 3, xc = (tid & 7) * 2;
    float2 pv, xv;
    auto loadT = [&](int v0) {
        pv = make_float2(0, 0); xv = make_float2(0, 0);
        int w = w0 + pr;
        if (w < N) pv = *(const float2*)&Pb[(size_t)w * PS + v0 + pc];
        int vv = v0 + xr;
        if (vv < N) xv = *(const float2*)&cat[((size_t)(b * N + vv)) * 240 + c0 + xc];
    };
    loadT(0);
    int cur = 0;
    for (int t = 0; t < 7; t++) {
        __syncthreads();
        sP[cur][pr][pc] = pv.x; sP[cur][pr][pc + 1] = pv.y;
        sX[cur][xr][xc] = xv.x; sX[cur][xr][xc + 1] = xv.y;
        if (t < 6) loadT((t + 1) * 32);
        __syncthreads();
#pragma unroll 8
        for (int v_ = 0; v_ < 32; v_++) a1 += sP[cur][ty][v_] * sX[cur][v_][tx];
        cur ^= 1;
    }
    int w = w0 + ty, c = c0 + tx;
    if (w < N) {
        size_t base = ((size_t)(b * N + w)) * 240;
        cat[base + 80 + c] = ALPHA * cat[base + c] + a1;
    }
}

// ---------------- gate: fused h2-prop + GEMM. cat holds [x|h1|*]; h2 computed into LDS ----------------
__global__ __launch_bounds__(256) void k_gate(
    const float* __restrict__ cat, const float* __restrict__ P,
    const float* __restrict__ Wa, const float* __restrict__ ba,
    const float* __restrict__ Wb, const float* __restrict__ bb,
    int baseMode,
    const float* __restrict__ xseq, int tsel, const float* __restrict__ xbuf,
    float* __restrict__ zbuf, float* __restrict__ ricat,
    float* __restrict__ h,
    const float* __restrict__ target,
    const float* __restrict__ Wlong, const float* __restrict__ blong,
    const float* __restrict__ Wfus, const float* __restrict__ bfus,
    float* __restrict__ out) {
    int mode = baseMode + blockIdx.z;
    const float* W = (mode == 1) ? Wb : Wa;
    const float* bias = (mode == 1) ? bb : ba;
    int b = blockIdx.y, w0 = blockIdx.x * 16;
    int tid = threadIdx.x, ty = tid >> 4, tx = tid & 15;
    const float* Pb = P + (size_t)b * PS * PS;
    __shared__ float sC[16][241];
    __shared__ float sP[16][33];
    __shared__ float sX[32][81];
    __shared__ float sW[48][65];
    __shared__ float hrow[16][65], trow[16][65];
    for (int l4 = tid; l4 < 640; l4 += 256) {
        int r = l4 / 40, c4 = (l4 % 40) * 4;
        int w = w0 + r;
        float4 v4 = make_float4(0, 0, 0, 0);
        if (w < N) v4 = *(const float4*)&cat[((size_t)(b * N + w)) * 240 + c4];
        sC[r][c4] = v4.x; sC[r][c4 + 1] = v4.y; sC[r][c4 + 2] = v4.z; sC[r][c4 + 3] = v4.w;
    }
    // phase A: h2 = ALPHA*x + P@h1 -> sC[...][160..240]
    float acc[5] = {0, 0, 0, 0, 0};
    int prr = tid >> 4, prc = (tid & 15) * 2;
    int xrow = tid & 31, xc0 = (tid >> 5) * 10;
    float2 pv;
    float2 xv[5];
    auto loadT = [&](int v0) {
        pv = make_float2(0, 0);
        int w = w0 + prr;
        if (w < N) pv = *(const float2*)&Pb[(size_t)w * PS + v0 + prc];
        int v = v0 + xrow;
#pragma unroll
        for (int k = 0; k < 5; k++) xv[k] = make_float2(0, 0);
        if (v < N) {
            const float* src = &cat[((size_t)(b * N + v)) * 240 + 80 + xc0];
#pragma unroll
            for (int k = 0; k < 5; k++) xv[k] = *(const float2*)&src[k * 2];
        }
    };
    loadT(0);
    for (int t = 0; t < 7; t++) {
        __syncthreads();
        sP[prr][prc] = pv.x; sP[prr][prc + 1] = pv.y;
#pragma unroll
        for (int k = 0; k < 5; k++) { sX[xrow][xc0 + 2 * k] = xv[k].x; sX[xrow][xc0 + 2 * k + 1] = xv[k].y; }
        if (t < 6) loadT((t + 1) * 32);
        __syncthreads();
#pragma unroll 8
        for (int v = 0; v < 32; v++) {
            float p = sP[ty][v];
#pragma unroll
            for (int j = 0; j < 5; j++) acc[j] += p * sX[v][tx * 5 + j];
        }
    }
#pragma unroll
    for (int j = 0; j < 5; j++) {
        int c = tx * 5 + j;
        sC[ty][160 + c] = ALPHA * sC[ty][c] + acc[j];
    }
    // phase B: GEMM over 240 cols with register prefetch
    float4 wv[3];
#pragma unroll
    for (int k = 0; k < 3; k++) wv[k] = *(const float4*)&W[(tid + k * 256) * 4];
    float ga[4];
#pragma unroll
    for (int j = 0; j < 4; j++) ga[j] = bias[tx * 4 + j];
    for (int ch = 0; ch < 5; ch++) {
        __syncthreads();
#pragma unroll
        for (int k = 0; k < 3; k++) {
            int l4 = tid + k * 256;
            int r = l4 >> 4, cc = (l4 & 15) * 4;
            sW[r][cc] = wv[k].x; sW[r][cc + 1] = wv[k].y; sW[r][cc + 2] = wv[k].z; sW[r][cc + 3] = wv[k].w;
        }
        if (ch < 4) {
#pragma unroll
            for (int k = 0; k < 3; k++) wv[k] = *(const float4*)&W[(size_t)(ch + 1) * 3072 + (tid + k * 256) * 4];
        }
        __syncthreads();
        int c0 = ch * 48;
#pragma unroll 8
        for (int cc = 0; cc < 48; cc++) {
            float cv = sC[ty][c0 + cc];
#pragma unroll
            for (int j = 0; j < 4; j++) ga[j] += cv * sW[cc][tx * 4 + j];
        }
    }
    int w = w0 + ty;
    bool valid = w < N;
    if (mode == 0) {
        if (valid) {
#pragma unroll
            for (int j = 0; j < 4; j++) zbuf[((size_t)(b * N + w)) * 64 + tx * 4 + j] = sigm(ga[j]);
        }
    } else if (mode == 1) {
        if (valid) {
#pragma unroll
            for (int j = 0; j < 4; j++) {
                int o = tx * 4 + j;
                ricat[((size_t)(b * N + w)) * 240 + 16 + o] = sigm(ga[j]) * h[((size_t)(b * N + w)) * 64 + o];
            }
            if (tx < 4) {
                const float* xp = (tsel >= 0) ? (xseq + ((size_t)(b * T + tsel)) * NF) : (xbuf + (size_t)b * NF);
#pragma unroll
                for (int j = 0; j < 4; j++) {
                    int c = tx * 4 + j;
                    ricat[((size_t)(b * N + w)) * 240 + c] = xp[w * F + c];
                }
            }
        }
    } else {
#pragma unroll
        for (int j = 0; j < 4; j++) {
            int o = tx * 4 + j;
            float cval = tanh_fast(ga[j]);
            float zv = 0.f, hv = 0.f;
            if (valid) { zv = zbuf[((size_t)(b * N + w)) * 64 + o]; hv = h[((size_t)(b * N + w)) * 64 + o]; }
            float hn = zv * hv + (1.f - zv) * cval;
            if (valid) h[((size_t)(b * N + w)) * 64 + o] = hn;
            hrow[ty][o] = valid ? hn : 0.f;
        }
        if (mode == 3) {
            for (int l = tid; l < 1024; l += 256) {
                int i = l >> 6, o = l & 63;
                int ww = w0 + i;
                trow[i][o] = (ww < N) ? target[((size_t)(b * N + ww)) * 64 + o] : 0.f;
            }
            __syncthreads();
            float lg = blong[tx];
            float fs = bfus[tx];
            for (int o = 0; o < 64; o++) {
                lg += hrow[ty][o] * Wlong[o * 16 + tx];
                fs += trow[ty][o] * Wfus[o * 16 + tx] + hrow[ty][o] * Wfus[(64 + o) * 16 + tx];
            }
            if (valid) {
                out[((size_t)1 * B * N + b * N + w) * 16 + tx] = lg;
                out[((size_t)2 * B * N + b * N + w) * 16 + tx] = fs;
            }
        }
    }
}

// ---------------- attention: fused q/k proj + 32x32 tile + TRANSPOSED store + rowsum ----------------
// attnT[m*PS+n] = exp(score(n,m)); rsum[n] = sum_m exp(score(n,m))
__global__ __launch_bounds__(256) void k_attn2(const float* __restrict__ inp,
                                               const float* __restrict__ Wq, const float* __restrict__ Wk,
                                               const float* __restrict__ kb, const float* __restrict__ sw_,
                                               float* __restrict__ attnT, float* __restrict__ rsum) {
    int bt = blockIdx.z, b = bt >> 2, tau = bt & 3;
    int n0 = blockIdx.x * 32, m0 = blockIdx.y * 32;
    int tid = threadIdx.x, ti = tid >> 4, tj = tid & 15;
    __shared__ float sQ[32][65], sK[32][65];
    __shared__ float sWq[16][64], sWk[16][64];
    __shared__ float sXq[32][17], sXk[32][17];
    __shared__ float ssw[64], skb[64];
    const float* xq = inp + ((size_t)(b * T + (T - 1))) * NF;
    const float* xk = inp + ((size_t)(b * T + 20 + tau)) * NF;
    {
        float4 wq4 = *(const float4*)&Wq[tid * 4];
        float4 wk4 = *(const float4*)&Wk[tid * 4];
        *(float4*)&sWq[tid >> 4][(tid & 15) * 4] = wq4;
        *(float4*)&sWk[tid >> 4][(tid & 15) * 4] = wk4;
        if (tid < 64) { ssw[tid] = sw_[tid]; skb[tid] = kb[tid]; }
        int idx = tid & 127;
        int r = idx >> 2, c4 = (idx & 3) * 4;
        if (tid < 128) {
            float4 a = make_float4(0, 0, 0, 0);
            int n = n0 + r;
            if (n < N) a = *(const float4*)&xq[(size_t)n * F + c4];
            sXq[r][c4] = a.x; sXq[r][c4 + 1] = a.y; sXq[r][c4 + 2] = a.z; sXq[r][c4 + 3] = a.w;
        } else {
            float4 c = make_float4(0, 0, 0, 0);
            int m = m0 + r;
            if (m < N) c = *(const float4*)&xk[(size_t)m * F + c4];
            sXk[r][c4] = c.x; sXk[r][c4 + 1] = c.y; sXk[r][c4 + 2] = c.z; sXk[r][c4 + 3] = c.w;
        }
    }
    __syncthreads();
    {
        int r = tid >> 3, o0 = (tid & 7) * 8;
        float xr[16], xkr[16];
#pragma unroll
        for (int f = 0; f < 16; f++) { xr[f] = sXq[r][f]; xkr[f] = sXk[r][f]; }
#pragma unroll
        for (int j = 0; j < 8; j++) {
            int o = o0 + j;
            float aq = 0.f, ak = skb[o];
#pragma unroll
            for (int f = 0; f < 16; f++) { aq += xr[f] * sWq[f][o]; ak += xkr[f] * sWk[f][o]; }
            sQ[r][o] = aq; sK[r][o] = ak;
        }
    }
    __syncthreads();
    float s00 = 0.f, s01 = 0.f, s10 = 0.f, s11 = 0.f;
#pragma unroll 2
    for (int d = 0; d < 64; d++) {
        float w = ssw[d];
        float q1 = sQ[ti][d], q2 = sQ[ti + 16][d];
        float k1 = sK[tj][d], k2 = sK[tj + 16][d];
        s00 += tanh_pnc(q1 + k1) * w;
        s01 += tanh_pnc(q1 + k2) * w;
        s10 += tanh_pnc(q2 + k1) * w;
        s11 += tanh_pnc(q2 + k2) * w;
    }
    int n1 = n0 + ti, n2 = n0 + ti + 16, m1 = m0 + tj, m2 = m0 + tj + 16;
    bool vn1 = n1 < N, vn2 = n2 < N, vm1 = m1 < N, vm2 = m2 < N;
    float e00 = (vn1 && vm1) ? __expf(s00) : 0.f;
    float e01 = (vn1 && vm2) ? __expf(s01) : 0.f;
    float e10 = (vn2 && vm1) ? __expf(s10) : 0.f;
    float e11 = (vn2 && vm2) ? __expf(s11) : 0.f;
    float part1 = e00 + e01, part2 = e10 + e11;
    for (int d = 8; d > 0; d >>= 1) {
        part1 += __shfl_down(part1, d, 16);
        part2 += __shfl_down(part2, d, 16);
    }
    if (tj == 0) {
        if (vn1) atomicAdd(&rsum[bt * N + n1], part1);
        if (vn2) atomicAdd(&rsum[bt * N + n2], part2);
    }
    // transposed store via LDS (reuse sQ as 32x33 tile): tile[m_local][n_local] = e
    __syncthreads();
    float* tile = &sQ[0][0];
    tile[tj * 33 + ti] = e00;
    tile[(tj + 16) * 33 + ti] = e01;
    tile[tj * 33 + ti + 16] = e10;
    tile[(tj + 16) * 33 + ti + 16] = e11;
    __syncthreads();
    {
        int row = tid >> 3, c4 = (tid & 7) * 4;
        int m = m0 + row;
        if (m < N) {
            float4 v = make_float4(tile[row * 33 + c4], tile[row * 33 + c4 + 1],
                                   tile[row * 33 + c4 + 2], tile[row * 33 + c4 + 3]);
            *(float4*)&attnT[(size_t)bt * PS * PS + (size_t)m * PS + n0 + c4] = v;
        }
    }
}

// ---------------- ssgal first prop (dual-P, double-buffered): x1 = a*x + G*(attnT/rs + Ts)@x ----------------
__global__ __launch_bounds__(256) void k_prop_xr(const float* __restrict__ attnT, const float* __restrict__ rsum,
                                                 const float* __restrict__ Ts, const float* __restrict__ inp,
                                                 float* __restrict__ x1) {
    int bt = blockIdx.y, w0 = blockIdx.x * 16;
    int b = bt >> 2, tau = bt & 3;
    const float* xb = inp + ((size_t)(b * T + 20 + tau)) * NF;
    const float* PA = attnT + (size_t)bt * PS * PS;
    int tid = threadIdx.x, ty = tid >> 4, tx = tid & 15;
    __shared__ float sPA[2][16][33], sPT[2][16][33];
    __shared__ float sX[2][32][17], sXs[2][32][17];
    float accA = 0.f, accT = 0.f;
    int prr = tid >> 3, pcc = (tid & 7) * 4;                  // tid<128: P tiles 16x32
    int xrr = (tid - 128) >> 2, xcc = ((tid - 128) & 3) * 4;  // tid>=128: X tile 32x16
    float4 pa, pt, xv;
    float rinv_;
    auto loadT = [&](int v0) {
        pa = make_float4(0, 0, 0, 0); pt = make_float4(0, 0, 0, 0); xv = make_float4(0, 0, 0, 0); rinv_ = 0.f;
        if (tid < 128) {
            int w = w0 + prr;
            if (w < N) {
                pa = *(const float4*)&PA[(size_t)w * PS + v0 + pcc];
                pt = *(const float4*)&Ts[(size_t)w * PS + v0 + pcc];
            }
        } else {
            int v = v0 + xrr;
            if (v < N) {
                xv = *(const float4*)&xb[(size_t)v * F + xcc];
                rinv_ = __builtin_amdgcn_rcpf(rsum[bt * N + v]);
            }
        }
    };
    loadT(0);
    int cur = 0;
    for (int t = 0; t < 7; t++) {
        __syncthreads();
        if (tid < 128) {
            sPA[cur][prr][pcc] = pa.x; sPA[cur][prr][pcc + 1] = pa.y; sPA[cur][prr][pcc + 2] = pa.z; sPA[cur][prr][pcc + 3] = pa.w;
            sPT[cur][prr][pcc] = pt.x; sPT[cur][prr][pcc + 1] = pt.y; sPT[cur][prr][pcc + 2] = pt.z; sPT[cur][prr][pcc + 3] = pt.w;
        } else {
            sX[cur][xrr][xcc] = xv.x; sX[cur][xrr][xcc + 1] = xv.y; sX[cur][xrr][xcc + 2] = xv.z; sX[cur][xrr][xcc + 3] = xv.w;
            sXs[cur][xrr][xcc] = xv.x * rinv_; sXs[cur][xrr][xcc + 1] = xv.y * rinv_;
            sXs[cur][xrr][xcc + 2] = xv.z * rinv_; sXs[cur][xrr][xcc + 3] = xv.w * rinv_;
        }
        if (t < 6) loadT((t + 1) * 32);
        __syncthreads();
#pragma unroll 8
        for (int v = 0; v < 32; v++) {
            accA += sPA[cur][ty][v] * sXs[cur][v][tx];
            accT += sPT[cur][ty][v] * sX[cur][v][tx];
        }
        cur ^= 1;
    }
    int w = w0 + ty;
    if (w < N) x1[((size_t)(bt * N + w)) * 16 + tx] = ALPHA * xb[w * F + tx] + GAMMA * (accA + accT);
}

// ---------------- ssgal second prop (dual-P) + projection + relu + tau-sum ----------------
__global__ __launch_bounds__(256) void k_sgc2(const float* __restrict__ attnT, const float* __restrict__ rsum,
                                              const float* __restrict__ Ts, const float* __restrict__ x1,
                                              const float* __restrict__ inp,
                                              const float* __restrict__ Ws, const float* __restrict__ bs,
                                              float* __restrict__ target) {
    int bt = blockIdx.y, b = bt >> 2, tau = bt & 3, w0 = blockIdx.x * 16;
    const float* xb = inp + ((size_t)(b * T + 20 + tau)) * NF;
    const float* PA = attnT + (size_t)bt * PS * PS;
    int tid = threadIdx.x, ty = tid >> 4, tx = tid & 15;
    __shared__ float sPA[2][16][33], sPT[2][16][33];
    __shared__ float sX[2][32][17], sXs[2][32][17];
    __shared__ float cat[16][48], sW[48][64];
    float accA = 0.f, accT = 0.f;
    int prr = tid >> 3, pcc = (tid & 7) * 4;
    int xrr = (tid - 128) >> 2, xcc = ((tid - 128) & 3) * 4;
    float4 pa, pt, xv;
    float rinv_;
    auto loadT = [&](int v0) {
        pa = make_float4(0, 0, 0, 0); pt = make_float4(0, 0, 0, 0); xv = make_float4(0, 0, 0, 0); rinv_ = 0.f;
        if (tid < 128) {
            int w = w0 + prr;
            if (w < N) {
                pa = *(const float4*)&PA[(size_t)w * PS + v0 + pcc];
                pt = *(const float4*)&Ts[(size_t)w * PS + v0 + pcc];
            }
        } else {
            int v = v0 + xrr;
            if (v < N) {
                xv = *(const float4*)&x1[((size_t)(bt * N + v)) * 16 + xcc];
                rinv_ = __builtin_amdgcn_rcpf(rsum[bt * N + v]);
            }
        }
    };
    loadT(0);
    int cur = 0;
    for (int t = 0; t < 7; t++) {
        __syncthreads();
        if (tid < 128) {
            sPA[cur][prr][pcc] = pa.x; sPA[cur][prr][pcc + 1] = pa.y; sPA[cur][prr][pcc + 2] = pa.z; sPA[cur][prr][pcc + 3] = pa.w;
            sPT[cur][prr][pcc] = pt.x; sPT[cur][prr][pcc + 1] = pt.y; sPT[cur][prr][pcc + 2] = pt.z; sPT[cur][prr][pcc + 3] = pt.w;
        } else {
            sX[cur][xrr][xcc] = xv.x; sX[cur][xrr][xcc + 1] = xv.y; sX[cur][xrr][xcc + 2] = xv.z; sX[cur][xrr][xcc + 3] = xv.w;
            sXs[cur][xrr][xcc] = xv.x * rinv_; sXs[cur][xrr][xcc + 1] = xv.y * rinv_;
            sXs[cur][xrr][xcc + 2] = xv.z * rinv_; sXs[cur][xrr][xcc + 3] = xv.w * rinv_;
        }
        if (t < 6) loadT((t + 1) * 32);
        __syncthreads();
#pragma unroll 8
        for (int v = 0; v < 32; v++) {
            accA += sPA[cur][ty][v] * sXs[cur][v][tx];
            accT += sPT[cur][ty][v] * sX[cur][v][tx];
        }
        cur ^= 1;
    }
    int w = w0 + ty;
    bool valid = w < N;
    __syncthreads();
    for (int l = tid; l < 512; l += 256) {
        int i = l >> 5, c = l & 31;
        int ww = w0 + i;
        float vv = 0;
        if (ww < N) {
            if (c < 16) vv = xb[ww * F + c];
            else vv = x1[((size_t)bt * N + ww) * 16 + (c - 16)];
        }
        cat[i][c] = vv;
    }
    {
        float x0 = valid ? xb[w * F + tx] : 0.f;
        cat[ty][32 + tx] = ALPHA * x0 + GAMMA * (accA + accT);
    }
    {
        float4 wv[3];
#pragma unroll
        for (int k = 0; k < 3; k++) wv[k] = *(const float4*)&Ws[(tid + k * 256) * 4];
#pragma unroll
        for (int k = 0; k < 3; k++) {
            int l4 = tid + k * 256;
            *(float4*)&sW[l4 >> 4][(l4 & 15) * 4] = wv[k];
        }
    }
    __syncthreads();
    float a[4];
#pragma unroll
    for (int j = 0; j < 4; j++) a[j] = bs[tx * 4 + j];
#pragma unroll 8
    for (int cc = 0; cc < 48; cc++) {
        float cv = cat[ty][cc];
#pragma unroll
        for (int j = 0; j < 4; j++) a[j] += cv * sW[cc][tx * 4 + j];
    }
    if (valid) {
#pragma unroll
        for (int j = 0; j < 4; j++) {
            float r = a[j] > 0.f ? a[j] : 0.f;
            atomicAdd(&target[(b * N + w) * 64 + tx * 4 + j], r);
        }
    }
}

// ---------------- short head ----------------
__global__ __launch_bounds__(256) void k_short(const float* __restrict__ target,
                                               const float* __restrict__ Wsh, const float* __restrict__ bsh,
                                               float* __restrict__ out, float* __restrict__ xshort) {
    int b = blockIdx.y, n0 = blockIdx.x * 16;
    int tid = threadIdx.x, ty = tid >> 4, tx = tid & 15;
    __shared__ float trow[16][65], sW[64][16];
    {
        int r = tid >> 4, c4 = (tid & 15) * 4;
        int n = n0 + r;
        float4 tv = make_float4(0, 0, 0, 0);
        if (n < N) tv = *(const float4*)&target[((size_t)(b * N + n)) * 64 + c4];
        trow[r][c4] = tv.x; trow[r][c4 + 1] = tv.y; trow[r][c4 + 2] = tv.z; trow[r][c4 + 3] = tv.w;
        float4 wv = *(const float4*)&Wsh[tid * 4];
        *(float4*)&sW[tid >> 2][(tid & 3) * 4] = wv;
    }
    __syncthreads();
    float a = bsh[tx];
#pragma unroll 8
    for (int o = 0; o < 64; o++) a += trow[ty][o] * sW[o][tx];
    int n = n0 + ty;
    if (n < N) {
        out[((size_t)0 * B * N + b * N + n) * 16 + tx] = a;
        xshort[(b * N + n) * 16 + tx] = a;
    }
}

extern "C" void kernel_launch(void* const* d_in, const int* in_sizes, int n_in,
                              void* d_out, int out_size, void* d_ws, size_t ws_size,
                              hipStream_t stream) {
    const float* inp = (const float*)d_in[0];
    const float* adj = (const float*)d_in[1];
    const float* src_gen_w = (const float*)d_in[2];
    const float* src_gen_b = (const float*)d_in[3];
    const float* tgt_gen_w = (const float*)d_in[4];
    const float* tgt_gen_b = (const float*)d_in[5];
    const float* src_emb_w = (const float*)d_in[6];
    const float* src_emb_b = (const float*)d_in[7];
    const float* tgt_emb_w = (const float*)d_in[8];
    const float* tgt_emb_b = (const float*)d_in[9];
    const float* gru_z_w = (const float*)d_in[10];
    const float* gru_z_b = (const float*)d_in[11];
    const float* gru_r_w = (const float*)d_in[12];
    const float* gru_r_b = (const float*)d_in[13];
    const float* gru_c_w = (const float*)d_in[14];
    const float* gru_c_b = (const float*)d_in[15];
    const float* attn_q_w = (const float*)d_in[16];
    const float* attn_k_w = (const float*)d_in[17];
    const float* attn_k_b = (const float*)d_in[18];
    const float* attn_s_w = (const float*)d_in[19];
    const float* sgcn_w = (const float*)d_in[20];
    const float* sgcn_b = (const float*)d_in[21];
    const float* short_w = (const float*)d_in[22];
    const float* short_b = (const float*)d_in[23];
    const float* long_w = (const float*)d_in[24];
    const float* long_b = (const float*)d_in[25];
    const float* fus_w = (const float*)d_in[26];
    const float* fus_b = (const float*)d_in[27];
    float* out = (float*)d_out;

    float* ws = (float*)d_ws;
    size_t off = 0;
    auto A = [&](size_t n) { n = (n + 3) & ~(size_t)3; float* p = ws + off; off += n; return p; };
    float* Ts = A((size_t)PS * PS);
    float* A2 = A((size_t)PS * PS);
    float* sbuf = A((size_t)B * N * DH);
    float* tbuf = A((size_t)B * N * DH);
    float* P = A((size_t)B * PS * PS);
    float* catg = A((size_t)B * N * 240);
    float* catc = A((size_t)B * N * 240);
    float* zb = A((size_t)B * N * 64);
    float* attnT = A((size_t)32 * PS * PS);
    float* x1 = A((size_t)32 * NF);
    float* xshort = A(BNF);
    size_t zero_begin = off;
    float* h = A((size_t)B * N * H);
    float* target = A((size_t)B * N * 64);
    float* rsum = A((size_t)32 * N);
    size_t zero_end = off;
    (void)ws_size; (void)in_sizes; (void)n_in; (void)out_size;

    // single memset zeroes h, target, rsum (adjacent allocations)
    hipMemsetAsync(h, 0, (zero_end - zero_begin) * sizeof(float), stream);
    k_build_Ts<<<(N * N + 255) / 256, 256, 0, stream>>>(adj, Ts);
    k_mm_sq<<<dim3(7, 7), 256, 0, stream>>>(Ts, A2);

    auto run_cell = [&](int tsel, const float* xbuf, int finalFlag) {
        k_cell_a<<<dim3(13, B, 2), 256, 0, stream>>>(h, Ts, A2, inp, tsel, xbuf,
                                                     src_gen_w, src_gen_b, tgt_gen_w, tgt_gen_b,
                                                     src_emb_w, src_emb_b, tgt_emb_w, tgt_emb_b, sbuf, tbuf, catg);
        k_cell_bP<<<dim3(13, B), 256, 0, stream>>>(sbuf, tbuf, adj, P);
        k_prop1<<<dim3(13, B, 5), 256, 0, stream>>>(P, catg);
        k_gate<<<dim3(13, B, 2), 256, 0, stream>>>(catg, P, gru_z_w, gru_z_b, gru_r_w, gru_r_b, 0,
                                                   inp, tsel, xbuf, zb, catc, h,
                                                   nullptr, nullptr, nullptr, nullptr, nullptr, nullptr);
        k_prop1<<<dim3(13, B, 5), 256, 0, stream>>>(P, catc);
        k_gate<<<dim3(13, B, 1), 256, 0, stream>>>(catc, P, gru_c_w, gru_c_b, nullptr, nullptr, 2 + finalFlag,
                                                   nullptr, 0, nullptr, zb, nullptr, h,
                                                   target, long_w, long_b, fus_w, fus_b, out);
    };

    for (int t = 0; t < 20; t += 4) run_cell(t, nullptr, 0);

    k_attn2<<<dim3(7, 7, 32), 256, 0, stream>>>(inp, attn_q_w, attn_k_w, attn_k_b, attn_s_w, attnT, rsum);
    k_prop_xr<<<dim3(13, 32), 256, 0, stream>>>(attnT, rsum, Ts, inp, x1);
    k_sgc2<<<dim3(13, 32), 256, 0, stream>>>(attnT, rsum, Ts, x1, inp, sgcn_w, sgcn_b, target);
    k_short<<<dim3(13, B), 256, 0, stream>>>(target, short_w, short_b, out, xshort);

    run_cell(-1, xshort, 1);
}